// Round 1
// baseline (157.411 us; speedup 1.0000x reference)
//
#include <hip/hip_runtime.h>

// ---------------- problem constants ----------------
#define NB    1024        // batch
#define NN    19          // nodes
#define NF    8           // filters per node
#define CCH   152         // conv channels = NN*NF
#define TLEN  512
#define TP    128         // pooled time
#define GO    16          // gcn out
#define KFLAT 38912       // NN*TP*GO
#define HID   128
#define NCLS  2

// GEMM split-K config
#define KTILE 512
#define NKT   (KFLAT / KTILE)   // 76

typedef float  f32x4  __attribute__((ext_vector_type(4)));
typedef __bf16 bf16x8 __attribute__((ext_vector_type(8)));
typedef __bf16 bf16x4 __attribute__((ext_vector_type(4)));
typedef unsigned short u16x8 __attribute__((ext_vector_type(8)));

// ---------------------------------------------------------------------------
// Kernel 1: per-batch fused front: conv(k5,depthwise groups=19 -> x8 filt)
//           + bias + BN(eval) + ReLU + maxpool4 + softmax(adj)-mix + gcn 8->16
//           + ReLU, emit g[b] as bf16 row of the FC1 GEMM A matrix.
// ---------------------------------------------------------------------------
__global__ __launch_bounds__(256) void fused_front(
    const float* __restrict__ x,        // [NB][NN][TLEN]
    const float* __restrict__ conv_w,   // [CCH][1][5]
    const float* __restrict__ conv_b,   // [CCH]
    const float* __restrict__ bn_gamma, const float* __restrict__ bn_beta,
    const float* __restrict__ bn_mean,  const float* __restrict__ bn_var,
    const float* __restrict__ adj,      // [NN][NN]
    const float* __restrict__ gcn_w,    // [GO][NF]
    const float* __restrict__ gcn_b,    // [GO]
    __bf16* __restrict__ g_out)         // [NB][KFLAT]  (n*2048 + t*16 + o)
{
    __shared__ __align__(16) float xs[NN][520];   // x padded: data at [2..514)
    __shared__ __align__(16) float hs[CCH * TP];  // [n][f][t] == [c][t]
    __shared__ float As[NN * NN];
    __shared__ float cs[CCH * 5];
    __shared__ float bnS[CCH], bnB[CCH];
    __shared__ float gws[GO * NF], gbs[GO];

    const int tid = threadIdx.x;
    const int b = blockIdx.x;

    // ---- stage small params / precompute fused BN affine ----
    for (int i = tid; i < CCH * 5; i += 256) cs[i] = conv_w[i];
    for (int i = tid; i < CCH; i += 256) {
        float inv = bn_gamma[i] * rsqrtf(bn_var[i] + 1e-5f);
        bnS[i] = inv;
        bnB[i] = conv_b[i] * inv + bn_beta[i] - bn_mean[i] * inv;
    }
    for (int i = tid; i < GO * NF; i += 256) gws[i] = gcn_w[i];
    for (int i = tid; i < GO; i += 256) gbs[i] = gcn_b[i];

    // ---- softmax(adj, axis=1): one thread per row ----
    if (tid < NN) {
        float v[NN];
        float m = -1e30f;
        #pragma unroll
        for (int j = 0; j < NN; ++j) { v[j] = adj[tid * NN + j]; m = fmaxf(m, v[j]); }
        float s = 0.f;
        #pragma unroll
        for (int j = 0; j < NN; ++j) { v[j] = expf(v[j] - m); s += v[j]; }
        float r = 1.f / s;
        #pragma unroll
        for (int j = 0; j < NN; ++j) As[tid * NN + j] = v[j] * r;
    }

    // ---- stage x[b] into LDS with 2-elem zero halo each side ----
    const float* xb = x + (size_t)b * (NN * TLEN);
    for (int i = tid; i < NN * TLEN; i += 256) {
        int n = i >> 9, t = i & 511;
        xs[n][t + 2] = xb[i];
    }
    if (tid < NN) { xs[tid][0] = 0.f; xs[tid][1] = 0.f; xs[tid][514] = 0.f; xs[tid][515] = 0.f; }
    __syncthreads();

    // ---- conv + BN + ReLU + maxpool4 -> hs[c][tp] ----
    for (int idx = tid; idx < CCH * TP; idx += 256) {
        int c = idx >> 7, tp = idx & 127;
        int n = c >> 3;
        int t0 = tp * 4;
        float w0 = cs[c*5+0], w1v = cs[c*5+1], w2v = cs[c*5+2], w3v = cs[c*5+3], w4v = cs[c*5+4];
        float S = bnS[c], Bb = bnB[c];
        const float* xr = &xs[n][t0];
        float m = -1e30f;
        #pragma unroll
        for (int p = 0; p < 4; ++p) {
            float acc = xr[p]*w0 + xr[p+1]*w1v + xr[p+2]*w2v + xr[p+3]*w3v + xr[p+4]*w4v;
            float z = acc * S + Bb;
            m = fmaxf(m, z);
        }
        hs[idx] = fmaxf(m, 0.f);   // relu(max z) == max(relu z)
    }
    __syncthreads();

    // ---- A-mix over nodes + gcn linear 8->16 + ReLU -> bf16 g row ----
    __bf16* grow = g_out + (size_t)b * KFLAT;
    for (int idx = tid; idx < NN * TP; idx += 256) {
        int n = idx >> 7, t = idx & 127;
        float sup[NF];
        #pragma unroll
        for (int f = 0; f < NF; ++f) sup[f] = 0.f;
        for (int j = 0; j < NN; ++j) {
            float a = As[n * NN + j];
            const float* hp = &hs[j * (NF * TP) + t];
            #pragma unroll
            for (int f = 0; f < NF; ++f) sup[f] += a * hp[f * TP];
        }
        union { __bf16 h[16]; u16x8 v[2]; } ov;
        #pragma unroll
        for (int o = 0; o < GO; ++o) {
            float v = gbs[o];
            #pragma unroll
            for (int f = 0; f < NF; ++f) v += sup[f] * gws[o * NF + f];
            ov.h[o] = (__bf16)fmaxf(v, 0.f);
        }
        u16x8* dst = (u16x8*)(grow + (size_t)(n * (TP * GO) + t * GO));
        dst[0] = ov.v[0];
        dst[1] = ov.v[1];
    }
}

// ---------------------------------------------------------------------------
// Kernel 2: w1 fp32 -> bf16 (row-major [HID][KFLAT], layout preserved)
// ---------------------------------------------------------------------------
__global__ __launch_bounds__(256) void w1_to_bf16(
    const float* __restrict__ w1, __bf16* __restrict__ o)
{
    const int n4 = (HID * KFLAT) >> 2;   // 1,245,184 float4s
    for (int i = blockIdx.x * 256 + threadIdx.x; i < n4; i += gridDim.x * 256) {
        float4 v = ((const float4*)w1)[i];
        bf16x4 r;
        r[0] = (__bf16)v.x; r[1] = (__bf16)v.y; r[2] = (__bf16)v.z; r[3] = (__bf16)v.w;
        ((bf16x4*)o)[i] = r;
    }
}

// ---------------------------------------------------------------------------
// Kernel 3: split-K bf16 MFMA GEMM: C[b,j] += sum_k g[b,k]*w1[j,k]
//   grid = (M/128=8, K/KTILE=76), block = 256 (4 waves, 2x2 of 64x64)
//   partial[ktile][b][j] fp32 (deterministic; reduced in kernel 4)
// ---------------------------------------------------------------------------
__global__ __launch_bounds__(256) void gemm_fc1(
    const __bf16* __restrict__ gmat,   // [NB][KFLAT]
    const __bf16* __restrict__ wmat,   // [HID][KFLAT]
    float* __restrict__ partial)       // [NKT][NB][HID]
{
    __shared__ __align__(16) __bf16 At[128][40];  // +8 pad: 80B row stride
    __shared__ __align__(16) __bf16 Bt[128][40];

    const int tid = threadIdx.x;
    const int b0 = blockIdx.x * 128;
    const int k0 = blockIdx.y * KTILE;

    const int lane = tid & 63;
    const int w = tid >> 6;
    const int wm = (w >> 1) * 64;
    const int wn = (w & 1) * 64;

    const int srow = tid >> 2;      // 0..63
    const int soct = tid & 3;       // k-octet 0..3

    f32x4 acc[4][4];
    #pragma unroll
    for (int m = 0; m < 4; ++m)
        #pragma unroll
        for (int n = 0; n < 4; ++n) acc[m][n] = (f32x4){0.f, 0.f, 0.f, 0.f};

    const int arow = lane & 15;
    const int aoct = (lane >> 4) * 8;

    for (int ks = 0; ks < KTILE / 32; ++ks) {
        const int gk = k0 + ks * 32 + soct * 8;
        // stage A (g rows = batches) and B (w1 rows = outputs), 16B per store
        *(u16x8*)&At[srow     ][soct * 8] = *(const u16x8*)(gmat + (size_t)(b0 + srow     ) * KFLAT + gk);
        *(u16x8*)&At[srow + 64][soct * 8] = *(const u16x8*)(gmat + (size_t)(b0 + srow + 64) * KFLAT + gk);
        *(u16x8*)&Bt[srow     ][soct * 8] = *(const u16x8*)(wmat + (size_t)(srow     ) * KFLAT + gk);
        *(u16x8*)&Bt[srow + 64][soct * 8] = *(const u16x8*)(wmat + (size_t)(srow + 64) * KFLAT + gk);
        __syncthreads();

        bf16x8 af[4], bfr[4];
        #pragma unroll
        for (int m = 0; m < 4; ++m) af[m]  = *(const bf16x8*)&At[wm + m * 16 + arow][aoct];
        #pragma unroll
        for (int n = 0; n < 4; ++n) bfr[n] = *(const bf16x8*)&Bt[wn + n * 16 + arow][aoct];
        #pragma unroll
        for (int m = 0; m < 4; ++m)
            #pragma unroll
            for (int n = 0; n < 4; ++n)
                acc[m][n] = __builtin_amdgcn_mfma_f32_16x16x32_bf16(af[m], bfr[n], acc[m][n], 0, 0, 0);
        __syncthreads();
    }

    // epilogue: C/D layout col = lane&15, row = (lane>>4)*4 + reg
    float* pout = partial + (size_t)blockIdx.y * (NB * HID);
    #pragma unroll
    for (int m = 0; m < 4; ++m) {
        const int rbase = b0 + wm + m * 16 + (lane >> 4) * 4;
        #pragma unroll
        for (int n = 0; n < 4; ++n) {
            const int col = wn + n * 16 + (lane & 15);
            #pragma unroll
            for (int r = 0; r < 4; ++r)
                pout[(size_t)(rbase + r) * HID + col] = acc[m][n][r];
        }
    }
}

// ---------------------------------------------------------------------------
// Kernel 4: reduce split-K partials + b1 + ReLU, then FC2 (128->2) + b2
// ---------------------------------------------------------------------------
__global__ __launch_bounds__(128) void reduce_fc2(
    const float* __restrict__ partial,  // [NKT][NB][HID]
    const float* __restrict__ b1,       // [HID]
    const float* __restrict__ w2,       // [NCLS][HID]
    const float* __restrict__ b2,       // [NCLS]
    float* __restrict__ out)            // [NB][NCLS]
{
    __shared__ float red0[128], red1[128];
    const int b = blockIdx.x, j = threadIdx.x;
    float s = b1[j];
    #pragma unroll 4
    for (int p = 0; p < NKT; ++p) s += partial[(size_t)p * (NB * HID) + b * HID + j];
    float h = fmaxf(s, 0.f);
    red0[j] = h * w2[j];
    red1[j] = h * w2[HID + j];
    __syncthreads();
    for (int off = 64; off > 0; off >>= 1) {
        if (j < off) { red0[j] += red0[j + off]; red1[j] += red1[j + off]; }
        __syncthreads();
    }
    if (j == 0) {
        out[b * 2 + 0] = red0[0] + b2[0];
        out[b * 2 + 1] = red1[0] + b2[1];
    }
}

// ---------------------------------------------------------------------------
extern "C" void kernel_launch(void* const* d_in, const int* in_sizes, int n_in,
                              void* d_out, int out_size, void* d_ws, size_t ws_size,
                              hipStream_t stream) {
    const float* x        = (const float*)d_in[0];
    const float* conv_w   = (const float*)d_in[1];
    const float* conv_b   = (const float*)d_in[2];
    const float* bn_gamma = (const float*)d_in[3];
    const float* bn_beta  = (const float*)d_in[4];
    const float* bn_mean  = (const float*)d_in[5];
    const float* bn_var   = (const float*)d_in[6];
    const float* adj      = (const float*)d_in[7];
    const float* gcn_w    = (const float*)d_in[8];
    const float* gcn_b    = (const float*)d_in[9];
    const float* w1       = (const float*)d_in[10];
    const float* b1       = (const float*)d_in[11];
    const float* w2       = (const float*)d_in[12];
    const float* b2       = (const float*)d_in[13];
    float* out = (float*)d_out;

    // workspace layout (total 129,499,136 B):
    //   g bf16   [1024][38912]  79,691,776 B
    //   w1 bf16  [128][38912]    9,961,472 B
    //   partial  [76][1024][128] fp32 39,845,888 B
    char* ws = (char*)d_ws;
    __bf16* gmat   = (__bf16*)ws;
    __bf16* w1b    = (__bf16*)(ws + 79691776);
    float*  part   = (float*)(ws + 79691776 + 9961472);

    fused_front<<<dim3(NB), dim3(256), 0, stream>>>(
        x, conv_w, conv_b, bn_gamma, bn_beta, bn_mean, bn_var, adj, gcn_w, gcn_b, gmat);
    w1_to_bf16<<<dim3(1024), dim3(256), 0, stream>>>(w1, w1b);
    gemm_fc1<<<dim3(8, NKT), dim3(256), 0, stream>>>(gmat, w1b, part);
    reduce_fc2<<<dim3(NB), dim3(128), 0, stream>>>(part, b1, w2, b2, out);
}